// Round 2
// baseline (430.644 us; speedup 1.0000x reference)
//
#include <hip/hip_runtime.h>
#include <math.h>

// GCN 2-layer (DGL GraphConv norm='both'), restructured. ALL inputs/outputs
// are float32 per the reference (round-1 NaN was a bf16-misread of f32 data).
//   out_norm = rsqrt(max(out_deg,1)), in_norm = rsqrt(max(in_deg,1))
//   featp = out_norm[:,None] * (feat @ W1)   (matmul BEFORE segment-sum: linearity)
//   agg1[dst] += featp[src]                  (64 f32 atomics / edge)
//   h1 = relu(in_norm[:,None]*agg1 + b1)
//   s  = out_norm * (h1 @ W2)                (W2 is 64->1: scalarize before edge pass)
//   agg2[dst] += s[src]                      (1 f32 atomic / edge)
//   out = sigmoid(in_norm*agg2 + b2)

__global__ void degree_kernel(const int* __restrict__ src, const int* __restrict__ dst,
                              float* __restrict__ out_deg, float* __restrict__ in_deg, int E) {
    int e = blockIdx.x * blockDim.x + threadIdx.x;
    if (e < E) {
        atomicAdd(&out_deg[src[e]], 1.0f);
        atomicAdd(&in_deg[dst[e]], 1.0f);
    }
}

__global__ void norm_kernel(const float* __restrict__ out_deg, const float* __restrict__ in_deg,
                            float* __restrict__ out_norm, float* __restrict__ in_norm, int N) {
    int n = blockIdx.x * blockDim.x + threadIdx.x;
    if (n < N) {
        out_norm[n] = rsqrtf(fmaxf(out_deg[n], 1.0f));
        in_norm[n]  = rsqrtf(fmaxf(in_deg[n], 1.0f));
    }
}

// featp = out_norm * (feat @ W1); one wave per row, lane = output column.
__global__ void featw1_kernel(const float* __restrict__ feat,
                              const float* __restrict__ W1,
                              const float* __restrict__ out_norm,
                              float* __restrict__ featp, int N) {
    __shared__ float w[64 * 64];
    int tid = threadIdx.x;
    for (int i = tid; i < 64 * 64; i += blockDim.x)
        w[i] = W1[i];
    __syncthreads();
    int wave = tid >> 6;
    int lane = tid & 63;
    int row = blockIdx.x * (blockDim.x >> 6) + wave;
    if (row >= N) return;
    float acc = 0.0f;
    #pragma unroll
    for (int k = 0; k < 64; k++) {
        float a = feat[row * 64 + k];      // wave-uniform broadcast load
        acc += a * w[k * 64 + lane];       // stride-1 across lanes: conflict-free
    }
    featp[row * 64 + lane] = out_norm[row] * acc;
}

// Layer-1 edge scatter: one wave per edge, lane = feature dim.
__global__ void edge1_kernel(const int* __restrict__ src, const int* __restrict__ dst,
                             const float* __restrict__ featp, float* __restrict__ agg1, int E) {
    int gid = blockIdx.x * blockDim.x + threadIdx.x;
    int e = gid >> 6;
    int lane = gid & 63;
    if (e < E) {
        int sn = src[e];
        int dn = dst[e];
        atomicAdd(&agg1[dn * 64 + lane], featp[sn * 64 + lane]);
    }
}

// h1 = relu(in_norm*agg1 + b1); s = out_norm * (h1 . W2). One wave per node.
__global__ void layer1_post_kernel(const float* __restrict__ agg1,
                                   const float* __restrict__ b1,
                                   const float* __restrict__ W2,
                                   const float* __restrict__ in_norm,
                                   const float* __restrict__ out_norm,
                                   float* __restrict__ s_buf, int N) {
    int gid = blockIdx.x * blockDim.x + threadIdx.x;
    int n = gid >> 6;
    int lane = gid & 63;
    if (n >= N) return;
    float h = fmaxf(in_norm[n] * agg1[n * 64 + lane] + b1[lane], 0.0f);
    float v = h * W2[lane];
    #pragma unroll
    for (int off = 32; off > 0; off >>= 1)
        v += __shfl_xor(v, off, 64);
    if (lane == 0) s_buf[n] = out_norm[n] * v;
}

// Layer-2 edge scatter: scalar per edge.
__global__ void edge2_kernel(const int* __restrict__ src, const int* __restrict__ dst,
                             const float* __restrict__ s_buf, float* __restrict__ agg2, int E) {
    int e = blockIdx.x * blockDim.x + threadIdx.x;
    if (e < E) {
        atomicAdd(&agg2[dst[e]], s_buf[src[e]]);
    }
}

__global__ void out_kernel(const float* __restrict__ agg2, const float* __restrict__ in_norm,
                           const float* __restrict__ b2,
                           float* __restrict__ out, int N) {
    int n = blockIdx.x * blockDim.x + threadIdx.x;
    if (n < N) {
        float x = in_norm[n] * agg2[n] + b2[0];
        out[n] = 1.0f / (1.0f + expf(-x));
    }
}

extern "C" void kernel_launch(void* const* d_in, const int* in_sizes, int n_in,
                              void* d_out, int out_size, void* d_ws, size_t ws_size,
                              hipStream_t stream) {
    const float* feat = (const float*)d_in[0];
    const float* W1   = (const float*)d_in[1];
    const float* b1   = (const float*)d_in[2];
    const float* W2   = (const float*)d_in[3];
    const float* b2   = (const float*)d_in[4];
    const int* src = (const int*)d_in[5];
    const int* dst = (const int*)d_in[6];
    float* out = (float*)d_out;

    const int N = in_sizes[0] / 64;   // 50000
    const int E = in_sizes[5];        // 800000

    float* ws = (float*)d_ws;
    float* out_deg  = ws;                 // N
    float* in_deg   = ws + (size_t)N;     // N
    float* agg2     = ws + (size_t)2 * N; // N   (contiguous with degs: one memset)
    float* out_norm = ws + (size_t)3 * N;
    float* in_norm  = ws + (size_t)4 * N;
    float* s_buf    = ws + (size_t)5 * N;
    float* featp    = ws + (size_t)6 * N;                  // N*64
    float* agg1     = ws + (size_t)6 * N + (size_t)64 * N; // N*64

    // Zero the atomic accumulators (ws is poisoned 0xAA before every call).
    hipMemsetAsync(ws, 0, (size_t)3 * N * sizeof(float), stream);
    hipMemsetAsync(agg1, 0, (size_t)64 * N * sizeof(float), stream);

    degree_kernel<<<(E + 255) / 256, 256, 0, stream>>>(src, dst, out_deg, in_deg, E);
    norm_kernel<<<(N + 255) / 256, 256, 0, stream>>>(out_deg, in_deg, out_norm, in_norm, N);
    featw1_kernel<<<(N + 3) / 4, 256, 0, stream>>>(feat, W1, out_norm, featp, N);
    {
        long long threads = (long long)E * 64;
        edge1_kernel<<<(int)((threads + 255) / 256), 256, 0, stream>>>(src, dst, featp, agg1, E);
    }
    layer1_post_kernel<<<(N * 64 + 255) / 256, 256, 0, stream>>>(agg1, b1, W2, in_norm, out_norm, s_buf, N);
    edge2_kernel<<<(E + 255) / 256, 256, 0, stream>>>(src, dst, s_buf, agg2, E);
    out_kernel<<<(N + 255) / 256, 256, 0, stream>>>(agg2, in_norm, b2, out, N);
}

// Round 4
// 325.055 us; speedup vs baseline: 1.3248x; 1.3248x over previous
//
#include <hip/hip_runtime.h>
#include <math.h>

// GCN 2-layer (DGL GraphConv norm='both'), CSR-restructured (no f32 atomics):
//   deg counts (int atomics) -> norms
//   row_start = exclusive_scan(in_deg)  (block sums + 1-block scan + final)
//   csr_src[row_start[d] + cursor[d]++] = src[e]     (counting-sort by dst)
//   featp = out_norm[:,None] * (feat @ W1)           (matmul BEFORE segment-sum)
//   s[n]  = out_norm[n] * (relu(in_norm[n]*sum_{e->n} featp[src] + b1) . W2)
//           (one wave/node over CSR segment; fused, no agg1 buffer)
//   out[n] = sigmoid(in_norm[n]*sum_{e->n} s[src] + b2)   (one thread/node)

#define BS 256

__global__ void degree_kernel(const int* __restrict__ src, const int* __restrict__ dst,
                              int* __restrict__ out_deg, int* __restrict__ in_deg, int E) {
    int e = blockIdx.x * blockDim.x + threadIdx.x;
    if (e < E) {
        atomicAdd(&out_deg[src[e]], 1);
        atomicAdd(&in_deg[dst[e]], 1);
    }
}

__global__ void norm_kernel(const int* __restrict__ out_deg, const int* __restrict__ in_deg,
                            float* __restrict__ out_norm, float* __restrict__ in_norm, int N) {
    int n = blockIdx.x * blockDim.x + threadIdx.x;
    if (n < N) {
        out_norm[n] = rsqrtf(fmaxf((float)out_deg[n], 1.0f));
        in_norm[n]  = rsqrtf(fmaxf((float)in_deg[n], 1.0f));
    }
}

// --- exclusive scan of in_deg -> row_start (3 kernels) ---
__global__ void block_sum_kernel(const int* __restrict__ deg, int* __restrict__ bsum, int N) {
    __shared__ int s[BS];
    int i = blockIdx.x * BS + threadIdx.x;
    s[threadIdx.x] = (i < N) ? deg[i] : 0;
    __syncthreads();
    for (int off = BS / 2; off > 0; off >>= 1) {
        if (threadIdx.x < off) s[threadIdx.x] += s[threadIdx.x + off];
        __syncthreads();
    }
    if (threadIdx.x == 0) bsum[blockIdx.x] = s[0];
}

__global__ void scan_bsum_kernel(const int* __restrict__ bsum, int* __restrict__ boff, int nb) {
    __shared__ int s[512];
    int t = threadIdx.x;
    for (int i = t; i < nb; i += blockDim.x) s[i] = bsum[i];
    __syncthreads();
    if (t == 0) {
        int acc = 0;
        for (int i = 0; i < nb; i++) { int v = s[i]; s[i] = acc; acc += v; }
    }
    __syncthreads();
    for (int i = t; i < nb; i += blockDim.x) boff[i] = s[i];
}

__global__ void scan_final_kernel(const int* __restrict__ deg, const int* __restrict__ boff,
                                  int* __restrict__ row_start, int N) {
    __shared__ int s[BS];
    int i = blockIdx.x * BS + threadIdx.x;
    int v = (i < N) ? deg[i] : 0;
    s[threadIdx.x] = v;
    __syncthreads();
    for (int off = 1; off < BS; off <<= 1) {
        int t = (threadIdx.x >= off) ? s[threadIdx.x - off] : 0;
        __syncthreads();
        s[threadIdx.x] += t;
        __syncthreads();
    }
    if (i < N) row_start[i] = boff[blockIdx.x] + s[threadIdx.x] - v;  // exclusive
}

__global__ void fill_csr_kernel(const int* __restrict__ src, const int* __restrict__ dst,
                                const int* __restrict__ row_start, int* __restrict__ cursor,
                                int* __restrict__ csr_src, int E) {
    int e = blockIdx.x * blockDim.x + threadIdx.x;
    if (e < E) {
        int d = dst[e];
        int pos = row_start[d] + atomicAdd(&cursor[d], 1);
        csr_src[pos] = src[e];
    }
}

// featp = out_norm * (feat @ W1); one wave per row, lane = output column.
__global__ void featw1_kernel(const float* __restrict__ feat,
                              const float* __restrict__ W1,
                              const float* __restrict__ out_norm,
                              float* __restrict__ featp, int N) {
    __shared__ float w[64 * 64];
    int tid = threadIdx.x;
    for (int i = tid; i < 64 * 64; i += blockDim.x)
        w[i] = W1[i];
    __syncthreads();
    int wave = tid >> 6;
    int lane = tid & 63;
    int row = blockIdx.x * (blockDim.x >> 6) + wave;
    if (row >= N) return;
    float acc = 0.0f;
    #pragma unroll
    for (int k = 0; k < 64; k++) {
        float a = feat[row * 64 + k];      // wave-uniform broadcast load
        acc += a * w[k * 64 + lane];       // stride-1 across lanes: conflict-free
    }
    featp[row * 64 + lane] = out_norm[row] * acc;
}

// Layer 1 fused: one wave per dst node; CSR segment sum + relu + dot(W2) + scale.
__global__ void csr_agg1_kernel(const int* __restrict__ row_start, const int* __restrict__ in_deg,
                                const int* __restrict__ csr_src,
                                const float* __restrict__ featp,
                                const float* __restrict__ b1, const float* __restrict__ W2,
                                const float* __restrict__ in_norm, const float* __restrict__ out_norm,
                                float* __restrict__ s_buf, int N) {
    int gid = blockIdx.x * blockDim.x + threadIdx.x;
    int n = gid >> 6;
    int lane = gid & 63;
    if (n >= N) return;
    int start = row_start[n];
    int deg = in_deg[n];
    float acc = 0.0f;
    for (int j = 0; j < deg; j++) {
        int sn = csr_src[start + j];                 // wave-uniform
        acc += featp[(size_t)sn * 64 + lane];        // coalesced 256B gather
    }
    float h = fmaxf(in_norm[n] * acc + b1[lane], 0.0f);
    float v = h * W2[lane];
    #pragma unroll
    for (int off = 32; off > 0; off >>= 1)
        v += __shfl_xor(v, off, 64);
    if (lane == 0) s_buf[n] = out_norm[n] * v;
}

// Layer 2 fused: one thread per dst node; scalar CSR sum + sigmoid -> out.
__global__ void csr_agg2_kernel(const int* __restrict__ row_start, const int* __restrict__ in_deg,
                                const int* __restrict__ csr_src,
                                const float* __restrict__ s_buf,
                                const float* __restrict__ in_norm, const float* __restrict__ b2,
                                float* __restrict__ out, int N) {
    int n = blockIdx.x * blockDim.x + threadIdx.x;
    if (n >= N) return;
    int start = row_start[n];
    int deg = in_deg[n];
    float a = 0.0f;
    for (int j = 0; j < deg; j++)
        a += s_buf[csr_src[start + j]];
    float x = in_norm[n] * a + b2[0];
    out[n] = 1.0f / (1.0f + expf(-x));
}

extern "C" void kernel_launch(void* const* d_in, const int* in_sizes, int n_in,
                              void* d_out, int out_size, void* d_ws, size_t ws_size,
                              hipStream_t stream) {
    const float* feat = (const float*)d_in[0];
    const float* W1   = (const float*)d_in[1];
    const float* b1   = (const float*)d_in[2];
    const float* W2   = (const float*)d_in[3];
    const float* b2   = (const float*)d_in[4];
    const int* src = (const int*)d_in[5];
    const int* dst = (const int*)d_in[6];
    float* out = (float*)d_out;

    const int N = in_sizes[0] / 64;   // 50000
    const int E = in_sizes[5];        // 800000
    const int nb = (N + BS - 1) / BS; // scan blocks (196)

    // workspace layout (all 4-byte elems); first 3N ints are the atomic
    // counters (out_deg, in_deg, cursor) zeroed by one memset
    int* wsi = (int*)d_ws;
    int* out_deg   = wsi;                            // N
    int* in_deg    = wsi + (size_t)N;                // N
    int* cursor    = wsi + (size_t)2 * N;            // N
    int* row_start = wsi + (size_t)3 * N;            // N
    int* bsum      = wsi + (size_t)4 * N;            // nb
    int* boff      = wsi + (size_t)4 * N + nb;       // nb
    int* csr_src   = wsi + (size_t)4 * N + 2 * nb;   // E
    float* fbase   = (float*)(wsi + (size_t)4 * N + 2 * nb + E);
    float* out_norm = fbase;                  // N
    float* in_norm  = fbase + (size_t)N;      // N
    float* s_buf    = fbase + (size_t)2 * N;  // N
    float* featp    = fbase + (size_t)3 * N;  // 64N

    hipMemsetAsync(wsi, 0, (size_t)3 * N * sizeof(int), stream);

    degree_kernel<<<(E + BS - 1) / BS, BS, 0, stream>>>(src, dst, out_deg, in_deg, E);
    norm_kernel<<<(N + BS - 1) / BS, BS, 0, stream>>>(out_deg, in_deg, out_norm, in_norm, N);
    block_sum_kernel<<<nb, BS, 0, stream>>>(in_deg, bsum, N);
    scan_bsum_kernel<<<1, 512, 0, stream>>>(bsum, boff, nb);
    scan_final_kernel<<<nb, BS, 0, stream>>>(in_deg, boff, row_start, N);
    fill_csr_kernel<<<(E + BS - 1) / BS, BS, 0, stream>>>(src, dst, row_start, cursor, csr_src, E);
    featw1_kernel<<<(N + 3) / 4, BS, 0, stream>>>(feat, W1, out_norm, featp, N);
    csr_agg1_kernel<<<(int)(((size_t)N * 64 + BS - 1) / BS), BS, 0, stream>>>(
        row_start, in_deg, csr_src, featp, b1, W2, in_norm, out_norm, s_buf, N);
    csr_agg2_kernel<<<(N + BS - 1) / BS, BS, 0, stream>>>(
        row_start, in_deg, csr_src, s_buf, in_norm, b2, out, N);
}

// Round 5
// 265.664 us; speedup vs baseline: 1.6210x; 1.2236x over previous
//
#include <hip/hip_runtime.h>
#include <hip/hip_fp16.h>
#include <math.h>

// GCN 2-layer (DGL GraphConv norm='both'), CSR + fp16 featp + 8-way MLP agg.
//   deg counts (int atomics) -> norms (fused into scan_final)
//   row_start = exclusive_scan(in_deg)
//   csr_src[row_start[d] + cursor[d]++] = src[e]     (counting-sort by dst)
//   featp = fp16( out_norm[:,None] * (feat @ W1) )   (matmul BEFORE segment-sum)
//   s[n]  = out_norm[n] * (relu(in_norm[n]*sum featp[src] + b1) . W2)
//           (one wave/node: 8 edge-groups x 8 fp16-feature-chunks, 16B gathers)
//   out[n] = sigmoid(in_norm[n]*sum s[src] + b2)     (16 lanes/node)

#define BS 256

__global__ void degree_kernel(const int* __restrict__ src, const int* __restrict__ dst,
                              int* __restrict__ out_deg, int* __restrict__ in_deg, int E) {
    int e = blockIdx.x * blockDim.x + threadIdx.x;
    if (e < E) {
        atomicAdd(&out_deg[src[e]], 1);
        atomicAdd(&in_deg[dst[e]], 1);
    }
}

__global__ void block_sum_kernel(const int* __restrict__ deg, int* __restrict__ bsum, int N) {
    __shared__ int s[BS];
    int i = blockIdx.x * BS + threadIdx.x;
    s[threadIdx.x] = (i < N) ? deg[i] : 0;
    __syncthreads();
    for (int off = BS / 2; off > 0; off >>= 1) {
        if (threadIdx.x < off) s[threadIdx.x] += s[threadIdx.x + off];
        __syncthreads();
    }
    if (threadIdx.x == 0) bsum[blockIdx.x] = s[0];
}

__global__ void scan_bsum_kernel(const int* __restrict__ bsum, int* __restrict__ boff, int nb) {
    __shared__ int s[512];
    int t = threadIdx.x;
    for (int i = t; i < nb; i += blockDim.x) s[i] = bsum[i];
    __syncthreads();
    if (t == 0) {
        int acc = 0;
        for (int i = 0; i < nb; i++) { int v = s[i]; s[i] = acc; acc += v; }
    }
    __syncthreads();
    for (int i = t; i < nb; i += blockDim.x) boff[i] = s[i];
}

// exclusive scan finalize + both norms (fused: saves a launch)
__global__ void scan_final_norm_kernel(const int* __restrict__ in_deg, const int* __restrict__ out_deg,
                                       const int* __restrict__ boff,
                                       int* __restrict__ row_start,
                                       float* __restrict__ out_norm, float* __restrict__ in_norm, int N) {
    __shared__ int s[BS];
    int i = blockIdx.x * BS + threadIdx.x;
    int v = (i < N) ? in_deg[i] : 0;
    s[threadIdx.x] = v;
    __syncthreads();
    for (int off = 1; off < BS; off <<= 1) {
        int t = (threadIdx.x >= off) ? s[threadIdx.x - off] : 0;
        __syncthreads();
        s[threadIdx.x] += t;
        __syncthreads();
    }
    if (i < N) {
        row_start[i] = boff[blockIdx.x] + s[threadIdx.x] - v;  // exclusive
        in_norm[i]   = rsqrtf(fmaxf((float)v, 1.0f));
        out_norm[i]  = rsqrtf(fmaxf((float)out_deg[i], 1.0f));
    }
}

__global__ void fill_csr_kernel(const int* __restrict__ src, const int* __restrict__ dst,
                                const int* __restrict__ row_start, int* __restrict__ cursor,
                                int* __restrict__ csr_src, int E) {
    int e = blockIdx.x * blockDim.x + threadIdx.x;
    if (e < E) {
        int d = dst[e];
        int pos = row_start[d] + atomicAdd(&cursor[d], 1);
        csr_src[pos] = src[e];
    }
}

// featp = fp16(out_norm * (feat @ W1)); one wave per row, lane = output column.
// feat row read as float4 broadcast (16 loads vs 64 scalar).
__global__ void featw1_kernel(const float* __restrict__ feat,
                              const float* __restrict__ W1,
                              const float* __restrict__ out_norm,
                              __half* __restrict__ featp, int N) {
    __shared__ float w[64 * 64];
    int tid = threadIdx.x;
    for (int i = tid; i < 64 * 16; i += blockDim.x)
        ((float4*)w)[i] = ((const float4*)W1)[i];
    __syncthreads();
    int wave = tid >> 6;
    int lane = tid & 63;
    int row = blockIdx.x * (blockDim.x >> 6) + wave;
    if (row >= N) return;
    const float4* fr = (const float4*)(feat + (size_t)row * 64);
    float acc = 0.0f;
    #pragma unroll
    for (int k4 = 0; k4 < 16; k4++) {
        float4 a = fr[k4];                        // wave-uniform broadcast
        acc += a.x * w[(4 * k4 + 0) * 64 + lane]; // lane stride-1: conflict-free
        acc += a.y * w[(4 * k4 + 1) * 64 + lane];
        acc += a.z * w[(4 * k4 + 2) * 64 + lane];
        acc += a.w * w[(4 * k4 + 3) * 64 + lane];
    }
    featp[(size_t)row * 64 + lane] = __float2half(out_norm[row] * acc);
}

// Layer 1 fused: one wave/node. Lanes = 8 edge-groups (g) x 8 feature-chunks (l).
// Each lane gathers 16B (8 fp16 feats) -> 8 independent gathers in flight.
__global__ void csr_agg1_kernel(const int* __restrict__ row_start, const int* __restrict__ in_deg,
                                const int* __restrict__ csr_src,
                                const __half* __restrict__ featp,
                                const float* __restrict__ b1, const float* __restrict__ W2,
                                const float* __restrict__ in_norm, const float* __restrict__ out_norm,
                                float* __restrict__ s_buf, int N) {
    int gid = blockIdx.x * blockDim.x + threadIdx.x;
    int n = gid >> 6;
    if (n >= N) return;
    int lane = threadIdx.x & 63;
    int g = lane >> 3;   // edge slot within batch of 8
    int l = lane & 7;    // feature chunk: features [8l, 8l+8)
    int start = row_start[n];
    int deg = in_deg[n];
    float acc[8] = {0, 0, 0, 0, 0, 0, 0, 0};
    const uint4* fp4 = (const uint4*)featp;      // 8 x uint4 per node (64 fp16)
    for (int j = 0; j < deg; j += 8) {
        int e = j + g;
        if (e < deg) {
            int sn = csr_src[start + e];         // 8 dwords, coalesced across wave
            uint4 q = fp4[(size_t)sn * 8 + l];   // 16B gather
            const __half2* h2 = (const __half2*)&q;
            #pragma unroll
            for (int c = 0; c < 4; c++) {
                float2 f = __half22float2(h2[c]);
                acc[2 * c]     += f.x;
                acc[2 * c + 1] += f.y;
            }
        }
    }
    // sum the 8 edge-groups (lanes differing in bits 3..5)
    #pragma unroll
    for (int off = 8; off < 64; off <<= 1) {
        #pragma unroll
        for (int c = 0; c < 8; c++)
            acc[c] += __shfl_xor(acc[c], off, 64);
    }
    // epilogue: h = relu(in_norm*acc + b1); v = h . W2 (chunk), then sum chunks
    float inn = in_norm[n];
    float v = 0.0f;
    #pragma unroll
    for (int c = 0; c < 8; c++) {
        float h = fmaxf(inn * acc[c] + b1[l * 8 + c], 0.0f);
        v += h * W2[l * 8 + c];
    }
    #pragma unroll
    for (int off = 1; off < 8; off <<= 1)
        v += __shfl_xor(v, off, 64);
    if (lane == 0) s_buf[n] = out_norm[n] * v;
}

// Layer 2 fused: 16 lanes per node; coalesced csr reads + parallel gather.
__global__ void csr_agg2_kernel(const int* __restrict__ row_start, const int* __restrict__ in_deg,
                                const int* __restrict__ csr_src,
                                const float* __restrict__ s_buf,
                                const float* __restrict__ in_norm, const float* __restrict__ b2,
                                float* __restrict__ out, int N) {
    int gid = blockIdx.x * blockDim.x + threadIdx.x;
    int n = gid >> 4;
    if (n >= N) return;
    int sub = gid & 15;
    int start = row_start[n];
    int deg = in_deg[n];
    float a = 0.0f;
    for (int j = sub; j < deg; j += 16)
        a += s_buf[csr_src[start + j]];
    #pragma unroll
    for (int off = 1; off < 16; off <<= 1)
        a += __shfl_xor(a, off, 64);
    if (sub == 0) {
        float x = in_norm[n] * a + b2[0];
        out[n] = 1.0f / (1.0f + expf(-x));
    }
}

extern "C" void kernel_launch(void* const* d_in, const int* in_sizes, int n_in,
                              void* d_out, int out_size, void* d_ws, size_t ws_size,
                              hipStream_t stream) {
    const float* feat = (const float*)d_in[0];
    const float* W1   = (const float*)d_in[1];
    const float* b1   = (const float*)d_in[2];
    const float* W2   = (const float*)d_in[3];
    const float* b2   = (const float*)d_in[4];
    const int* src = (const int*)d_in[5];
    const int* dst = (const int*)d_in[6];
    float* out = (float*)d_out;

    const int N = in_sizes[0] / 64;   // 50000
    const int E = in_sizes[5];        // 800000
    const int nb = (N + BS - 1) / BS; // scan blocks

    // workspace layout: int region | fp16 featp (16B-aligned) | float region
    char* wsb = (char*)d_ws;
    int* out_deg   = (int*)wsb;                      // N
    int* in_deg    = out_deg + N;                    // N
    int* cursor    = in_deg + N;                     // N   (first 3N zeroed)
    int* row_start = cursor + N;                     // N
    int* bsum      = row_start + N;                  // nb
    int* boff      = bsum + nb;                      // nb
    int* csr_src   = boff + nb;                      // E
    size_t int_bytes = ((size_t)4 * N + 2 * nb + E) * sizeof(int);
    size_t half_off = (int_bytes + 15) & ~(size_t)15;
    __half* featp = (__half*)(wsb + half_off);       // 64N fp16 (16B-aligned)
    float* fbase  = (float*)(wsb + half_off + (size_t)64 * N * sizeof(__half));
    float* out_norm = fbase;                         // N
    float* in_norm  = fbase + (size_t)N;             // N
    float* s_buf    = fbase + (size_t)2 * N;         // N

    hipMemsetAsync(wsb, 0, (size_t)3 * N * sizeof(int), stream);

    degree_kernel<<<(E + BS - 1) / BS, BS, 0, stream>>>(src, dst, out_deg, in_deg, E);
    block_sum_kernel<<<nb, BS, 0, stream>>>(in_deg, bsum, N);
    scan_bsum_kernel<<<1, 512, 0, stream>>>(bsum, boff, nb);
    scan_final_norm_kernel<<<nb, BS, 0, stream>>>(in_deg, out_deg, boff, row_start, out_norm, in_norm, N);
    fill_csr_kernel<<<(E + BS - 1) / BS, BS, 0, stream>>>(src, dst, row_start, cursor, csr_src, E);
    featw1_kernel<<<(N + 3) / 4, BS, 0, stream>>>(feat, W1, out_norm, featp, N);
    csr_agg1_kernel<<<(int)(((size_t)N * 64 + BS - 1) / BS), BS, 0, stream>>>(
        row_start, in_deg, csr_src, featp, b1, W2, in_norm, out_norm, s_buf, N);
    csr_agg2_kernel<<<(int)(((size_t)N * 16 + BS - 1) / BS), BS, 0, stream>>>(
        row_start, in_deg, csr_src, s_buf, in_norm, b2, out, N);
}

// Round 6
// 228.457 us; speedup vs baseline: 1.8850x; 1.1629x over previous
//
#include <hip/hip_runtime.h>
#include <hip/hip_fp16.h>
#include <math.h>

// GCN 2-layer (DGL GraphConv norm='both'), CSR via rank-atomics:
//   rank[e] = atomicAdd(&in_cnt[dst[e]], 1)    -> in_cnt becomes in_deg
//   row_start = exclusive_scan(in_deg); in_norm fused into scan finalize
//   fill: csr_src[row_start[dst[e]] + rank[e]] = src[e]  (NO atomics)
//         + atomicAdd(&out_deg[src[e]], 1)     (out-degree rides along)
//   featp = fp16( rsqrt(out_deg) * (feat @ W1) )
//   s[n]  = rsqrt(out_deg[n]) * (relu(in_norm[n]*sum featp[src] + b1) . W2)
//   out[n] = sigmoid(in_norm[n]*sum s[src] + b2)

#define BS 256

// Pass 1: in-degree cursor WITH returned rank (the only atomic-with-return pass).
__global__ void rank_kernel(const int* __restrict__ dst, int* __restrict__ in_cnt,
                            int* __restrict__ rank, int E) {
    int e = blockIdx.x * blockDim.x + threadIdx.x;
    if (e < E) {
        rank[e] = atomicAdd(&in_cnt[dst[e]], 1);
    }
}

__global__ void block_sum_kernel(const int* __restrict__ deg, int* __restrict__ bsum, int N) {
    __shared__ int s[BS];
    int i = blockIdx.x * BS + threadIdx.x;
    s[threadIdx.x] = (i < N) ? deg[i] : 0;
    __syncthreads();
    for (int off = BS / 2; off > 0; off >>= 1) {
        if (threadIdx.x < off) s[threadIdx.x] += s[threadIdx.x + off];
        __syncthreads();
    }
    if (threadIdx.x == 0) bsum[blockIdx.x] = s[0];
}

__global__ void scan_bsum_kernel(const int* __restrict__ bsum, int* __restrict__ boff, int nb) {
    __shared__ int s[512];
    int t = threadIdx.x;
    for (int i = t; i < nb; i += blockDim.x) s[i] = bsum[i];
    __syncthreads();
    if (t == 0) {
        int acc = 0;
        for (int i = 0; i < nb; i++) { int v = s[i]; s[i] = acc; acc += v; }
    }
    __syncthreads();
    for (int i = t; i < nb; i += blockDim.x) boff[i] = s[i];
}

// exclusive scan finalize + in_norm (out_norm folded into consumers later)
__global__ void scan_final_kernel(const int* __restrict__ in_deg, const int* __restrict__ boff,
                                  int* __restrict__ row_start, float* __restrict__ in_norm, int N) {
    __shared__ int s[BS];
    int i = blockIdx.x * BS + threadIdx.x;
    int v = (i < N) ? in_deg[i] : 0;
    s[threadIdx.x] = v;
    __syncthreads();
    for (int off = 1; off < BS; off <<= 1) {
        int t = (threadIdx.x >= off) ? s[threadIdx.x - off] : 0;
        __syncthreads();
        s[threadIdx.x] += t;
        __syncthreads();
    }
    if (i < N) {
        row_start[i] = boff[blockIdx.x] + s[threadIdx.x] - v;  // exclusive
        in_norm[i]   = rsqrtf(fmaxf((float)v, 1.0f));
    }
}

// Pass 2: atomic-free CSR scatter + out-degree count (no-return atomics).
__global__ void fill_csr_kernel(const int* __restrict__ src, const int* __restrict__ dst,
                                const int* __restrict__ rank, const int* __restrict__ row_start,
                                int* __restrict__ csr_src, int* __restrict__ out_deg, int E) {
    int e = blockIdx.x * blockDim.x + threadIdx.x;
    if (e < E) {
        int sn = src[e];
        csr_src[row_start[dst[e]] + rank[e]] = sn;
        atomicAdd(&out_deg[sn], 1);
    }
}

// featp = fp16(rsqrt(out_deg) * (feat @ W1)); one wave per row, lane = out column.
__global__ void featw1_kernel(const float* __restrict__ feat,
                              const float* __restrict__ W1,
                              const int* __restrict__ out_deg,
                              __half* __restrict__ featp, int N) {
    __shared__ float w[64 * 64];
    int tid = threadIdx.x;
    for (int i = tid; i < 64 * 16; i += blockDim.x)
        ((float4*)w)[i] = ((const float4*)W1)[i];
    __syncthreads();
    int wave = tid >> 6;
    int lane = tid & 63;
    int row = blockIdx.x * (blockDim.x >> 6) + wave;
    if (row >= N) return;
    const float4* fr = (const float4*)(feat + (size_t)row * 64);
    float acc = 0.0f;
    #pragma unroll
    for (int k4 = 0; k4 < 16; k4++) {
        float4 a = fr[k4];                        // wave-uniform broadcast
        acc += a.x * w[(4 * k4 + 0) * 64 + lane]; // lane stride-1: conflict-free
        acc += a.y * w[(4 * k4 + 1) * 64 + lane];
        acc += a.z * w[(4 * k4 + 2) * 64 + lane];
        acc += a.w * w[(4 * k4 + 3) * 64 + lane];
    }
    float onorm = rsqrtf(fmaxf((float)out_deg[row], 1.0f));
    featp[(size_t)row * 64 + lane] = __float2half(onorm * acc);
}

// Layer 1 fused: one wave/node. Lanes = 8 edge-groups (g) x 8 feature-chunks (l).
// Each lane gathers 16B (8 fp16 feats) -> 8 independent gathers in flight.
__global__ void csr_agg1_kernel(const int* __restrict__ row_start, const int* __restrict__ in_deg,
                                const int* __restrict__ csr_src,
                                const __half* __restrict__ featp,
                                const float* __restrict__ b1, const float* __restrict__ W2,
                                const float* __restrict__ in_norm, const int* __restrict__ out_deg,
                                float* __restrict__ s_buf, int N) {
    int gid = blockIdx.x * blockDim.x + threadIdx.x;
    int n = gid >> 6;
    if (n >= N) return;
    int lane = threadIdx.x & 63;
    int g = lane >> 3;   // edge slot within batch of 8
    int l = lane & 7;    // feature chunk: features [8l, 8l+8)
    int start = row_start[n];
    int deg = in_deg[n];
    float acc[8] = {0, 0, 0, 0, 0, 0, 0, 0};
    const uint4* fp4 = (const uint4*)featp;      // 8 x uint4 per node (64 fp16)
    for (int j = 0; j < deg; j += 8) {
        int e = j + g;
        if (e < deg) {
            int sn = csr_src[start + e];         // 8 dwords, broadcast across lanes
            uint4 q = fp4[(size_t)sn * 8 + l];   // 16B gather
            const __half2* h2 = (const __half2*)&q;
            #pragma unroll
            for (int c = 0; c < 4; c++) {
                float2 f = __half22float2(h2[c]);
                acc[2 * c]     += f.x;
                acc[2 * c + 1] += f.y;
            }
        }
    }
    // sum the 8 edge-groups (lanes differing in bits 3..5)
    #pragma unroll
    for (int off = 8; off < 64; off <<= 1) {
        #pragma unroll
        for (int c = 0; c < 8; c++)
            acc[c] += __shfl_xor(acc[c], off, 64);
    }
    // epilogue: h = relu(in_norm*acc + b1); v = h . W2 (chunk), then sum chunks
    float inn = in_norm[n];
    float v = 0.0f;
    #pragma unroll
    for (int c = 0; c < 8; c++) {
        float h = fmaxf(inn * acc[c] + b1[l * 8 + c], 0.0f);
        v += h * W2[l * 8 + c];
    }
    #pragma unroll
    for (int off = 1; off < 8; off <<= 1)
        v += __shfl_xor(v, off, 64);
    if (lane == 0) {
        float onorm = rsqrtf(fmaxf((float)out_deg[n], 1.0f));
        s_buf[n] = onorm * v;
    }
}

// Layer 2 fused: 16 lanes per node; coalesced csr reads + parallel gather.
__global__ void csr_agg2_kernel(const int* __restrict__ row_start, const int* __restrict__ in_deg,
                                const int* __restrict__ csr_src,
                                const float* __restrict__ s_buf,
                                const float* __restrict__ in_norm, const float* __restrict__ b2,
                                float* __restrict__ out, int N) {
    int gid = blockIdx.x * blockDim.x + threadIdx.x;
    int n = gid >> 4;
    if (n >= N) return;
    int sub = gid & 15;
    int start = row_start[n];
    int deg = in_deg[n];
    float a = 0.0f;
    for (int j = sub; j < deg; j += 16)
        a += s_buf[csr_src[start + j]];
    #pragma unroll
    for (int off = 1; off < 16; off <<= 1)
        a += __shfl_xor(a, off, 64);
    if (sub == 0) {
        float x = in_norm[n] * a + b2[0];
        out[n] = 1.0f / (1.0f + expf(-x));
    }
}

extern "C" void kernel_launch(void* const* d_in, const int* in_sizes, int n_in,
                              void* d_out, int out_size, void* d_ws, size_t ws_size,
                              hipStream_t stream) {
    const float* feat = (const float*)d_in[0];
    const float* W1   = (const float*)d_in[1];
    const float* b1   = (const float*)d_in[2];
    const float* W2   = (const float*)d_in[3];
    const float* b2   = (const float*)d_in[4];
    const int* src = (const int*)d_in[5];
    const int* dst = (const int*)d_in[6];
    float* out = (float*)d_out;

    const int N = in_sizes[0] / 64;   // 50000
    const int E = in_sizes[5];        // 800000
    const int nb = (N + BS - 1) / BS; // scan blocks

    // workspace layout: int region | fp16 featp (16B-aligned) | float region
    char* wsb = (char*)d_ws;
    int* out_deg   = (int*)wsb;                      // N  (zeroed)
    int* in_cnt    = out_deg + N;                    // N  (zeroed; becomes in_deg)
    int* row_start = in_cnt + N;                     // N
    int* bsum      = row_start + N;                  // nb
    int* boff      = bsum + nb;                      // nb
    int* rank      = boff + nb;                      // E
    int* csr_src   = rank + E;                       // E
    size_t int_bytes = ((size_t)3 * N + 2 * nb + 2 * (size_t)E) * sizeof(int);
    size_t half_off = (int_bytes + 15) & ~(size_t)15;
    __half* featp = (__half*)(wsb + half_off);       // 64N fp16 (16B-aligned)
    float* fbase  = (float*)(wsb + half_off + (size_t)64 * N * sizeof(__half));
    float* in_norm = fbase;                          // N
    float* s_buf   = fbase + (size_t)N;              // N

    hipMemsetAsync(wsb, 0, (size_t)2 * N * sizeof(int), stream);

    rank_kernel<<<(E + BS - 1) / BS, BS, 0, stream>>>(dst, in_cnt, rank, E);
    block_sum_kernel<<<nb, BS, 0, stream>>>(in_cnt, bsum, N);
    scan_bsum_kernel<<<1, 512, 0, stream>>>(bsum, boff, nb);
    scan_final_kernel<<<nb, BS, 0, stream>>>(in_cnt, boff, row_start, in_norm, N);
    fill_csr_kernel<<<(E + BS - 1) / BS, BS, 0, stream>>>(src, dst, rank, row_start, csr_src, out_deg, E);
    featw1_kernel<<<(N + 3) / 4, BS, 0, stream>>>(feat, W1, out_deg, featp, N);
    csr_agg1_kernel<<<(int)(((size_t)N * 64 + BS - 1) / BS), BS, 0, stream>>>(
        row_start, in_cnt, csr_src, featp, b1, W2, in_norm, out_deg, s_buf, N);
    csr_agg2_kernel<<<(int)(((size_t)N * 16 + BS - 1) / BS), BS, 0, stream>>>(
        row_start, in_cnt, csr_src, s_buf, in_norm, b2, out, N);
}